// Round 8
// baseline (80.437 us; speedup 1.0000x reference)
//
#include <hip/hip_runtime.h>

// MMD loss, atomic-free, 3 kernels (fusion experiments R3/R4 proved the
// last-block-done sync costs ~2x what it saves on gfx950). ws layout:
//   [0, 16640)        float2 partial[2080]   per-block {S_same, S_all}
//   [16640, 82176)    float  sqpart[4][N]    row-norm partials (one per k-quarter)
//   [82176, +2*N*D)   uint4  fbt[N*D/8]      bf16 feature, TILED k-major:
//        chunk (rt, kc, r) -> index rt*(D/8)*64 + kc*64 + r   (16B chunks)

typedef __attribute__((ext_vector_type(8))) short short8;
typedef __attribute__((ext_vector_type(4))) float floatx4;

__device__ inline unsigned f2bf2(float lo, float hi) {
  union { float f; unsigned u; } a, b; a.f = lo; b.f = hi;
  unsigned ra = (a.u + 0x7fffu + ((a.u >> 16) & 1u)) >> 16;
  unsigned rb = (b.u + 0x7fffu + ((b.u >> 16) & 1u)) >> 16;
  return ra | (rb << 16);
}

__device__ inline float fast_exp2(float x) {
#if __has_builtin(__builtin_amdgcn_exp2f)
  return __builtin_amdgcn_exp2f(x);
#else
  return exp2f(x);
#endif
}

// Grid: (N/64)*4 blocks. Block = (rt = bid>>2, kq = bid&3). Coalesced fbt
// writes; row-norm partial per kq.
__global__ __launch_bounds__(256) void prep_kernel(
    const float* __restrict__ feat, uint4* __restrict__ fbt,
    float* __restrict__ sqpart, int N, int D) {
  const int tid = threadIdx.x;
  const int rt = blockIdx.x >> 2;
  const int kq = blockIdx.x & 3;
  const int r = tid & 63;
  const int nkc = D >> 3;                     // 32 chunks of 8 cols
  __shared__ float sqp[256];
  float ss = 0.f;
  #pragma unroll
  for (int it = 0; it < 2; ++it) {
    const int kc = kq * 8 + it * 4 + (tid >> 6);
    const float4* src = (const float4*)(feat + (size_t)(rt * 64 + r) * D + kc * 8);
    float4 v0 = src[0], v1 = src[1];
    ss += v0.x*v0.x + v0.y*v0.y + v0.z*v0.z + v0.w*v0.w
        + v1.x*v1.x + v1.y*v1.y + v1.z*v1.z + v1.w*v1.w;
    uint4 o;
    o.x = f2bf2(v0.x, v0.y); o.y = f2bf2(v0.z, v0.w);
    o.z = f2bf2(v1.x, v1.y); o.w = f2bf2(v1.z, v1.w);
    fbt[(size_t)rt * nkc * 64 + kc * 64 + r] = o;
  }
  sqp[tid] = ss;
  __syncthreads();
  if (tid < 64)
    sqpart[(size_t)kq * N + rt * 64 + tid] =
        sqp[tid] + sqp[tid + 64] + sqp[tid + 128] + sqp[tid + 192];
}

// One 64x64 tile pair per block (upper triangle), 256 thr = 4 waves.
// A and B fragments read DIRECTLY from fbt (2 MB, L2-resident) — no LDS
// staging. __launch_bounds__(256, 8): request 8 blocks/CU (32 waves/CU),
// forcing the allocator under the 64-VGPR occupancy cliff — the audited
// working set (~58 peak) fits. Epilogue: all 16 d^2 first; threads whose
// min d^2 >= 64 use the truncated 4-sigma sum (bit-identical there:
// dropped group sums to <= 2^-46 < 0.5 ulp of kk).
__global__ __launch_bounds__(256, 8) void mmd_main(
    const uint4* __restrict__ fbt, const float* __restrict__ sqpart,
    const int* __restrict__ dom, float2* __restrict__ partial, int N) {
  int b = blockIdx.x;
  int i = (int)((sqrtf(8.f * (float)b + 1.f) - 1.f) * 0.5f);
  while ((i + 1) * (i + 2) / 2 <= b) ++i;
  while (i * (i + 1) / 2 > b) --i;
  const int ti = b - i * (i + 1) / 2;
  const int tj = i;
  const int rowI = ti * 64, rowJ = tj * 64;

  __shared__ float sqI[64], sqJ[64];
  __shared__ int dmI[64], dmJ[64];
  __shared__ float red[8];

  const int tid = threadIdx.x;
  const int lane = tid & 63, w = tid >> 6;
  const int quad = lane >> 4, m16 = lane & 15;

  const uint4* At = fbt + (size_t)ti * 2048;
  const uint4* Bt = fbt + (size_t)tj * 2048;

  short8 afrag[8];
  #pragma unroll
  for (int s = 0; s < 8; ++s) {
    uint4 t = At[(s * 4 + quad) * 64 + w * 16 + m16];
    afrag[s] = *(short8*)&t;
  }

  if (tid < 64) {
    sqI[tid] = sqpart[rowI + tid] + sqpart[N + rowI + tid]
             + sqpart[2 * N + rowI + tid] + sqpart[3 * N + rowI + tid];
    dmI[tid] = dom[rowI + tid];
  } else if (tid < 128) {
    int t = tid - 64;
    sqJ[t] = sqpart[rowJ + t] + sqpart[N + rowJ + t]
           + sqpart[2 * N + rowJ + t] + sqpart[3 * N + rowJ + t];
    dmJ[t] = dom[rowJ + t];
  }
  __syncthreads();   // sq/dm visible

  floatx4 acc[4];
  #pragma unroll
  for (int t = 0; t < 4; ++t) acc[t] = (floatx4){0.f, 0.f, 0.f, 0.f};

  #pragma unroll
  for (int s = 0; s < 8; ++s) {
    // 4 independent B-chunk loads per s (wave-coalesced 256B segments,
    // identical addresses across the 4 waves -> L1 hits), then 4 MFMAs.
    uint4 b0 = Bt[(s * 4 + quad) * 64 + 0 * 16 + m16];
    uint4 b1 = Bt[(s * 4 + quad) * 64 + 1 * 16 + m16];
    uint4 b2 = Bt[(s * 4 + quad) * 64 + 2 * 16 + m16];
    uint4 b3 = Bt[(s * 4 + quad) * 64 + 3 * 16 + m16];
    acc[0] = __builtin_amdgcn_mfma_f32_16x16x32_bf16(afrag[s], *(short8*)&b0, acc[0], 0, 0, 0);
    acc[1] = __builtin_amdgcn_mfma_f32_16x16x32_bf16(afrag[s], *(short8*)&b1, acc[1], 0, 0, 0);
    acc[2] = __builtin_amdgcn_mfma_f32_16x16x32_bf16(afrag[s], *(short8*)&b2, acc[2], 0, 0, 0);
    acc[3] = __builtin_amdgcn_mfma_f32_16x16x32_bf16(afrag[s], *(short8*)&b3, acc[3], 0, 0, 0);
  }

  // c_s = -0.5*log2(e)*sigma for sigma in {1e-4,1e-3,1e-2,0.1,1,5,100};
  // sigma 10..30 built from powers of the sigma=5 term.
  const float C0 = -7.2134752e-05f, C1 = -7.2134752e-04f, C2 = -7.2134752e-03f,
              C3 = -7.2134752e-02f, C4 = -0.72134752f, C5 = -3.6067376f,
              C100 = -72.13475204f;

  // Hoist LDS scalars to registers (pure load hoisting; values identical).
  float sIr[4], sJr[4];
  int dIr[4], dJr[4];
  #pragma unroll
  for (int reg = 0; reg < 4; ++reg) {
    const int r = w * 16 + quad * 4 + reg;
    sIr[reg] = sqI[r]; dIr[reg] = dmI[r];
  }
  #pragma unroll
  for (int t = 0; t < 4; ++t) {
    const int c = t * 16 + m16;
    sJr[t] = sqJ[c]; dJr[t] = dmJ[c];
  }

  // Pass 1: all 16 d^2 (baseline-verbatim expression) + per-thread min.
  float d2v[16];
  float dmin = 3.4e38f;
  #pragma unroll
  for (int t = 0; t < 4; ++t) {
    const int gj = rowJ + t * 16 + m16;
    #pragma unroll
    for (int reg = 0; reg < 4; ++reg) {
      const int gi = rowI + w * 16 + quad * 4 + reg;
      float d2 = sIr[reg] + sJr[t] - 2.f * acc[t][reg];
      d2 = fmaxf(d2, 0.f);
      if (gi == gj) d2 = 0.f;                  // diagonal exact: k=12 dominates
      d2v[t * 4 + reg] = d2;
      dmin = fminf(dmin, d2);
    }
  }

  float s_all = 0.f, s_same = 0.f;
  if (__builtin_expect(dmin < 64.f, 0)) {
    // Full 12-sigma path (baseline-verbatim): diagonal/near threads only.
    #pragma unroll
    for (int t = 0; t < 4; ++t) {
      #pragma unroll
      for (int reg = 0; reg < 4; ++reg) {
        const float d2 = d2v[t * 4 + reg];
        float e0 = fast_exp2(d2 * C0), e1 = fast_exp2(d2 * C1);
        float e2 = fast_exp2(d2 * C2), e3 = fast_exp2(d2 * C3);
        float e4 = fast_exp2(d2 * C4), e5 = fast_exp2(d2 * C5);
        float e11 = fast_exp2(d2 * C100);
        float t10 = e5 * e5, t15 = t10 * e5, t20 = t10 * t10;
        float t25 = t15 * t10, t30 = t15 * t15;
        float kk = ((e0 + e1) + (e2 + e3)) + ((e4 + e5) + (t10 + t15))
                 + ((t20 + t25) + (t30 + e11));
        s_all += kk;
        if (dIr[reg] == dJr[t]) s_same += kk;
      }
    }
  } else {
    // Truncated path: for d2 >= 64 the dropped groups sum to <= 2^-46 and
    // the baseline's kk adds of them are bit-exact no-ops. Same serial
    // accumulation order as baseline -> bit-identical s_all/s_same.
    #pragma unroll
    for (int t = 0; t < 4; ++t) {
      #pragma unroll
      for (int reg = 0; reg < 4; ++reg) {
        const float d2 = d2v[t * 4 + reg];
        float e0 = fast_exp2(d2 * C0), e1 = fast_exp2(d2 * C1);
        float e2 = fast_exp2(d2 * C2), e3 = fast_exp2(d2 * C3);
        float kk = (e0 + e1) + (e2 + e3);
        s_all += kk;
        if (dIr[reg] == dJr[t]) s_same += kk;
      }
    }
  }

  #pragma unroll
  for (int off = 32; off > 0; off >>= 1) {
    s_all  += __shfl_down(s_all, off);
    s_same += __shfl_down(s_same, off);
  }
  if (lane == 0) { red[w] = s_all; red[4 + w] = s_same; }
  __syncthreads();
  if (tid == 0) {
    const float wt = (ti == tj) ? 1.f : 2.f;   // off-diag tiles count twice
    float a = (red[0] + red[1] + red[2] + red[3]) * wt;
    float s = (red[4] + red[5] + red[6] + red[7]) * wt;
    partial[b] = make_float2(s, a);
  }
}

__global__ __launch_bounds__(256) void finalize_kernel(
    const float2* __restrict__ partial, int nblk,
    const int* __restrict__ dom, float* __restrict__ out, int N) {
  __shared__ int histL[16];
  __shared__ double redS[8];
  const int tid = threadIdx.x;
  if (tid < 16) histL[tid] = 0;
  __syncthreads();

  double as = 0.0, aa = 0.0;
  if (nblk == 2080) {
    // Batched path: 8 independent loads issued up-front (latency hidden
    // under the histogram pass), consumed in the exact original per-thread
    // order -> bit-identical double sums.
    float2 v[8];
    #pragma unroll
    for (int k = 0; k < 8; ++k) v[k] = partial[tid + (k << 8)];
    const bool has9 = tid < (2080 - 2048);
    float2 v8 = has9 ? partial[tid + 2048] : make_float2(0.f, 0.f);
    #pragma unroll 4
    for (int i = tid; i < N; i += 256) atomicAdd(&histL[dom[i] & 15], 1);
    #pragma unroll
    for (int k = 0; k < 8; ++k) { as += (double)v[k].x; aa += (double)v[k].y; }
    if (has9) { as += (double)v8.x; aa += (double)v8.y; }
  } else {
    #pragma unroll 4
    for (int i = tid; i < N; i += 256) atomicAdd(&histL[dom[i] & 15], 1);
    for (int i = tid; i < nblk; i += 256) {
      float2 p = partial[i];
      as += (double)p.x; aa += (double)p.y;
    }
  }

  #pragma unroll
  for (int off = 32; off > 0; off >>= 1) {
    as += __shfl_down(as, off);
    aa += __shfl_down(aa, off);
  }
  const int w = tid >> 6;
  if ((tid & 63) == 0) { redS[w] = as; redS[4 + w] = aa; }
  __syncthreads();
  if (tid == 0) {
    double S = redS[0] + redS[1] + redS[2] + redS[3];
    double A = redS[4] + redS[5] + redS[6] + redS[7];
    double csame = 0.0;
    for (int i = 0; i < 16; ++i) { double h = (double)histL[i]; csame += h * h; }
    double call = (double)N * (double)N;
    out[0] = (float)(S / csame - (A - S) / (call - csame));
  }
}

extern "C" void kernel_launch(void* const* d_in, const int* in_sizes, int n_in,
                              void* d_out, int out_size, void* d_ws, size_t ws_size,
                              hipStream_t stream) {
  const float* feat = (const float*)d_in[0];
  const int* dom = (const int*)d_in[1];
  float* out = (float*)d_out;
  const int N = in_sizes[1];
  const int D = in_sizes[0] / N;
  const int T = N / 64;
  const int nblk = T * (T + 1) / 2;

  char* ws = (char*)d_ws;
  float2* partial = (float2*)ws;                       // 8*nblk = 16640 B
  float* sqpart = (float*)(ws + 16640);                // 4*N floats = 65536 B
  uint4* fbt = (uint4*)(ws + 82176);                   // 2*N*D B, 16-aligned

  prep_kernel<<<dim3(T * 4), dim3(256), 0, stream>>>(feat, fbt, sqpart, N, D);
  mmd_main<<<dim3(nblk), dim3(256), 0, stream>>>(fbt, sqpart, dom, partial, N);
  finalize_kernel<<<1, 256, 0, stream>>>(partial, nblk, dom, out, N);
}

// Round 9
// 77.525 us; speedup vs baseline: 1.0376x; 1.0376x over previous
//
#include <hip/hip_runtime.h>

// MMD loss, atomic-free, 3 kernels (fusion experiments R3/R4 proved the
// last-block-done sync costs ~2x what it saves on gfx950; R8 proved the
// occupancy bound regresses — the 2080-block grid is one resident round).
// ws layout:
//   [0, 16640)        float2 partial[2080]   per-block {S_same, S_all}
//   [16640, 82176)    float  sqpart[4][N]    row-norm partials (one per k-quarter)
//   [82176, +2*N*D)   uint4  fbt[N*D/8]      bf16 feature, TILED k-major:
//        chunk (rt, kc, r) -> index rt*(D/8)*64 + kc*64 + r   (16B chunks)

typedef __attribute__((ext_vector_type(8))) short short8;
typedef __attribute__((ext_vector_type(4))) float floatx4;

__device__ inline unsigned f2bf2(float lo, float hi) {
  union { float f; unsigned u; } a, b; a.f = lo; b.f = hi;
  unsigned ra = (a.u + 0x7fffu + ((a.u >> 16) & 1u)) >> 16;
  unsigned rb = (b.u + 0x7fffu + ((b.u >> 16) & 1u)) >> 16;
  return ra | (rb << 16);
}

__device__ inline float fast_exp2(float x) {
#if __has_builtin(__builtin_amdgcn_exp2f)
  return __builtin_amdgcn_exp2f(x);
#else
  return exp2f(x);
#endif
}

// Grid: (N/64)*4 blocks. Block = (rt = bid>>2, kq = bid&3). Coalesced fbt
// writes; row-norm partial per kq.
__global__ __launch_bounds__(256) void prep_kernel(
    const float* __restrict__ feat, uint4* __restrict__ fbt,
    float* __restrict__ sqpart, int N, int D) {
  const int tid = threadIdx.x;
  const int rt = blockIdx.x >> 2;
  const int kq = blockIdx.x & 3;
  const int r = tid & 63;
  const int nkc = D >> 3;                     // 32 chunks of 8 cols
  __shared__ float sqp[256];
  float ss = 0.f;
  #pragma unroll
  for (int it = 0; it < 2; ++it) {
    const int kc = kq * 8 + it * 4 + (tid >> 6);
    const float4* src = (const float4*)(feat + (size_t)(rt * 64 + r) * D + kc * 8);
    float4 v0 = src[0], v1 = src[1];
    ss += v0.x*v0.x + v0.y*v0.y + v0.z*v0.z + v0.w*v0.w
        + v1.x*v1.x + v1.y*v1.y + v1.z*v1.z + v1.w*v1.w;
    uint4 o;
    o.x = f2bf2(v0.x, v0.y); o.y = f2bf2(v0.z, v0.w);
    o.z = f2bf2(v1.x, v1.y); o.w = f2bf2(v1.z, v1.w);
    fbt[(size_t)rt * nkc * 64 + kc * 64 + r] = o;
  }
  sqp[tid] = ss;
  __syncthreads();
  if (tid < 64)
    sqpart[(size_t)kq * N + rt * 64 + tid] =
        sqp[tid] + sqp[tid + 64] + sqp[tid + 128] + sqp[tid + 192];
}

// One 64x64 tile pair per block (upper triangle), 256 thr = 4 waves.
// A and B fragments read DIRECTLY from fbt (2 MB, L2-resident; the 4-way
// per-chunk wave redundancy is L1-absorbed) — no LDS staging. LDS drops to
// ~1 KB so occupancy is VGPR-capped instead of 4 blocks/CU. Epilogue: all
// 16 d^2 first; threads whose min d^2 >= 64 use the truncated 4-sigma sum
// (bit-identical there: dropped group sums to <= 2^-46 < 0.5 ulp of kk).
__global__ __launch_bounds__(256) void mmd_main(
    const uint4* __restrict__ fbt, const float* __restrict__ sqpart,
    const int* __restrict__ dom, float2* __restrict__ partial, int N) {
  int b = blockIdx.x;
  int i = (int)((sqrtf(8.f * (float)b + 1.f) - 1.f) * 0.5f);
  while ((i + 1) * (i + 2) / 2 <= b) ++i;
  while (i * (i + 1) / 2 > b) --i;
  const int ti = b - i * (i + 1) / 2;
  const int tj = i;
  const int rowI = ti * 64, rowJ = tj * 64;

  __shared__ float sqI[64], sqJ[64];
  __shared__ int dmI[64], dmJ[64];
  __shared__ float red[8];

  const int tid = threadIdx.x;
  const int lane = tid & 63, w = tid >> 6;
  const int quad = lane >> 4, m16 = lane & 15;

  const uint4* At = fbt + (size_t)ti * 2048;
  const uint4* Bt = fbt + (size_t)tj * 2048;

  short8 afrag[8];
  #pragma unroll
  for (int s = 0; s < 8; ++s) {
    uint4 t = At[(s * 4 + quad) * 64 + w * 16 + m16];
    afrag[s] = *(short8*)&t;
  }

  if (tid < 64) {
    sqI[tid] = sqpart[rowI + tid] + sqpart[N + rowI + tid]
             + sqpart[2 * N + rowI + tid] + sqpart[3 * N + rowI + tid];
    dmI[tid] = dom[rowI + tid];
  } else if (tid < 128) {
    int t = tid - 64;
    sqJ[t] = sqpart[rowJ + t] + sqpart[N + rowJ + t]
           + sqpart[2 * N + rowJ + t] + sqpart[3 * N + rowJ + t];
    dmJ[t] = dom[rowJ + t];
  }
  __syncthreads();   // sq/dm visible

  floatx4 acc[4];
  #pragma unroll
  for (int t = 0; t < 4; ++t) acc[t] = (floatx4){0.f, 0.f, 0.f, 0.f};

  #pragma unroll
  for (int s = 0; s < 8; ++s) {
    // 4 independent B-chunk loads per s (wave-coalesced 256B segments,
    // identical addresses across the 4 waves -> L1 hits), then 4 MFMAs.
    uint4 b0 = Bt[(s * 4 + quad) * 64 + 0 * 16 + m16];
    uint4 b1 = Bt[(s * 4 + quad) * 64 + 1 * 16 + m16];
    uint4 b2 = Bt[(s * 4 + quad) * 64 + 2 * 16 + m16];
    uint4 b3 = Bt[(s * 4 + quad) * 64 + 3 * 16 + m16];
    acc[0] = __builtin_amdgcn_mfma_f32_16x16x32_bf16(afrag[s], *(short8*)&b0, acc[0], 0, 0, 0);
    acc[1] = __builtin_amdgcn_mfma_f32_16x16x32_bf16(afrag[s], *(short8*)&b1, acc[1], 0, 0, 0);
    acc[2] = __builtin_amdgcn_mfma_f32_16x16x32_bf16(afrag[s], *(short8*)&b2, acc[2], 0, 0, 0);
    acc[3] = __builtin_amdgcn_mfma_f32_16x16x32_bf16(afrag[s], *(short8*)&b3, acc[3], 0, 0, 0);
  }

  // c_s = -0.5*log2(e)*sigma for sigma in {1e-4,1e-3,1e-2,0.1,1,5,100};
  // sigma 10..30 built from powers of the sigma=5 term.
  const float C0 = -7.2134752e-05f, C1 = -7.2134752e-04f, C2 = -7.2134752e-03f,
              C3 = -7.2134752e-02f, C4 = -0.72134752f, C5 = -3.6067376f,
              C100 = -72.13475204f;

  // Hoist LDS scalars to registers (pure load hoisting; values identical).
  float sIr[4], sJr[4];
  int dIr[4], dJr[4];
  #pragma unroll
  for (int reg = 0; reg < 4; ++reg) {
    const int r = w * 16 + quad * 4 + reg;
    sIr[reg] = sqI[r]; dIr[reg] = dmI[r];
  }
  #pragma unroll
  for (int t = 0; t < 4; ++t) {
    const int c = t * 16 + m16;
    sJr[t] = sqJ[c]; dJr[t] = dmJ[c];
  }

  // Pass 1: all 16 d^2 (baseline-verbatim expression) + per-thread min.
  float d2v[16];
  float dmin = 3.4e38f;
  #pragma unroll
  for (int t = 0; t < 4; ++t) {
    const int gj = rowJ + t * 16 + m16;
    #pragma unroll
    for (int reg = 0; reg < 4; ++reg) {
      const int gi = rowI + w * 16 + quad * 4 + reg;
      float d2 = sIr[reg] + sJr[t] - 2.f * acc[t][reg];
      d2 = fmaxf(d2, 0.f);
      if (gi == gj) d2 = 0.f;                  // diagonal exact: k=12 dominates
      d2v[t * 4 + reg] = d2;
      dmin = fminf(dmin, d2);
    }
  }

  float s_all = 0.f, s_same = 0.f;
  if (__builtin_expect(dmin < 64.f, 0)) {
    // Full 12-sigma path (baseline-verbatim): diagonal/near threads only.
    #pragma unroll
    for (int t = 0; t < 4; ++t) {
      #pragma unroll
      for (int reg = 0; reg < 4; ++reg) {
        const float d2 = d2v[t * 4 + reg];
        float e0 = fast_exp2(d2 * C0), e1 = fast_exp2(d2 * C1);
        float e2 = fast_exp2(d2 * C2), e3 = fast_exp2(d2 * C3);
        float e4 = fast_exp2(d2 * C4), e5 = fast_exp2(d2 * C5);
        float e11 = fast_exp2(d2 * C100);
        float t10 = e5 * e5, t15 = t10 * e5, t20 = t10 * t10;
        float t25 = t15 * t10, t30 = t15 * t15;
        float kk = ((e0 + e1) + (e2 + e3)) + ((e4 + e5) + (t10 + t15))
                 + ((t20 + t25) + (t30 + e11));
        s_all += kk;
        if (dIr[reg] == dJr[t]) s_same += kk;
      }
    }
  } else {
    // Truncated path: for d2 >= 64 the dropped groups sum to <= 2^-46 and
    // the baseline's kk adds of them are bit-exact no-ops. Same serial
    // accumulation order as baseline -> bit-identical s_all/s_same.
    #pragma unroll
    for (int t = 0; t < 4; ++t) {
      #pragma unroll
      for (int reg = 0; reg < 4; ++reg) {
        const float d2 = d2v[t * 4 + reg];
        float e0 = fast_exp2(d2 * C0), e1 = fast_exp2(d2 * C1);
        float e2 = fast_exp2(d2 * C2), e3 = fast_exp2(d2 * C3);
        float kk = (e0 + e1) + (e2 + e3);
        s_all += kk;
        if (dIr[reg] == dJr[t]) s_same += kk;
      }
    }
  }

  #pragma unroll
  for (int off = 32; off > 0; off >>= 1) {
    s_all  += __shfl_down(s_all, off);
    s_same += __shfl_down(s_same, off);
  }
  if (lane == 0) { red[w] = s_all; red[4 + w] = s_same; }
  __syncthreads();
  if (tid == 0) {
    const float wt = (ti == tj) ? 1.f : 2.f;   // off-diag tiles count twice
    float a = (red[0] + red[1] + red[2] + red[3]) * wt;
    float s = (red[4] + red[5] + red[6] + red[7]) * wt;
    partial[b] = make_float2(s, a);
  }
}

__global__ __launch_bounds__(256) void finalize_kernel(
    const float2* __restrict__ partial, int nblk,
    const int* __restrict__ dom, float* __restrict__ out, int N) {
  __shared__ int histL[16];
  __shared__ double redS[8];
  const int tid = threadIdx.x;
  if (tid < 16) histL[tid] = 0;
  __syncthreads();

  double as = 0.0, aa = 0.0;
  if (nblk == 2080) {
    // Batched path: 8 independent loads issued up-front (latency hidden
    // under the histogram pass), consumed in the exact original per-thread
    // order -> bit-identical double sums.
    float2 v[8];
    #pragma unroll
    for (int k = 0; k < 8; ++k) v[k] = partial[tid + (k << 8)];
    const bool has9 = tid < (2080 - 2048);
    float2 v8 = has9 ? partial[tid + 2048] : make_float2(0.f, 0.f);
    #pragma unroll 4
    for (int i = tid; i < N; i += 256) atomicAdd(&histL[dom[i] & 15], 1);
    #pragma unroll
    for (int k = 0; k < 8; ++k) { as += (double)v[k].x; aa += (double)v[k].y; }
    if (has9) { as += (double)v8.x; aa += (double)v8.y; }
  } else {
    #pragma unroll 4
    for (int i = tid; i < N; i += 256) atomicAdd(&histL[dom[i] & 15], 1);
    for (int i = tid; i < nblk; i += 256) {
      float2 p = partial[i];
      as += (double)p.x; aa += (double)p.y;
    }
  }

  #pragma unroll
  for (int off = 32; off > 0; off >>= 1) {
    as += __shfl_down(as, off);
    aa += __shfl_down(aa, off);
  }
  const int w = tid >> 6;
  if ((tid & 63) == 0) { redS[w] = as; redS[4 + w] = aa; }
  __syncthreads();
  if (tid == 0) {
    double S = redS[0] + redS[1] + redS[2] + redS[3];
    double A = redS[4] + redS[5] + redS[6] + redS[7];
    double csame = 0.0;
    for (int i = 0; i < 16; ++i) { double h = (double)histL[i]; csame += h * h; }
    double call = (double)N * (double)N;
    out[0] = (float)(S / csame - (A - S) / (call - csame));
  }
}

extern "C" void kernel_launch(void* const* d_in, const int* in_sizes, int n_in,
                              void* d_out, int out_size, void* d_ws, size_t ws_size,
                              hipStream_t stream) {
  const float* feat = (const float*)d_in[0];
  const int* dom = (const int*)d_in[1];
  float* out = (float*)d_out;
  const int N = in_sizes[1];
  const int D = in_sizes[0] / N;
  const int T = N / 64;
  const int nblk = T * (T + 1) / 2;

  char* ws = (char*)d_ws;
  float2* partial = (float2*)ws;                       // 8*nblk = 16640 B
  float* sqpart = (float*)(ws + 16640);                // 4*N floats = 65536 B
  uint4* fbt = (uint4*)(ws + 82176);                   // 2*N*D B, 16-aligned

  prep_kernel<<<dim3(T * 4), dim3(256), 0, stream>>>(feat, fbt, sqpart, N, D);
  mmd_main<<<dim3(nblk), dim3(256), 0, stream>>>(fbt, sqpart, dom, partial, N);
  finalize_kernel<<<1, 256, 0, stream>>>(partial, nblk, dom, out, N);
}